// Round 14
// baseline (433.014 us; speedup 1.0000x reference)
//
#include <hip/hip_runtime.h>
#include <cstdint>
#include <cstddef>

#define B_   2
#define S_   2048
#define D_   1024
#define HQ_  16
#define HKV_ 4
#define HD_  64
#define P_   4096

using frag8 = __attribute__((ext_vector_type(8))) short;   // 8 bf16 (4 VGPRs)
using f32x4 = __attribute__((ext_vector_type(4))) float;   // 4 fp32 acc

__device__ __forceinline__ uint16_t f2b(float f) {
  uint32_t u = __builtin_bit_cast(uint32_t, f);
  u += 0x7fffu + ((u >> 16) & 1u);          // RNE
  return (uint16_t)(u >> 16);
}
__device__ __forceinline__ float b2f(uint16_t h) {
  return __builtin_bit_cast(float, (uint32_t)h << 16);
}

// async global->LDS, 16B per lane. LDS dest = wave-uniform base + lane*16 (HW rule).
__device__ __forceinline__ void gl16(const uint16_t* g, uint16_t* l) {
  __builtin_amdgcn_global_load_lds(
      (const __attribute__((address_space(1))) void*)g,
      (__attribute__((address_space(3))) void*)l, 16, 0, 0);
}

// runtime-dtype scalar load/store (f32: buffer is float; else bf16)
__device__ __forceinline__ float ldr(const void* p, size_t i, bool f32) {
  return f32 ? ((const float*)p)[i] : b2f(((const uint16_t*)p)[i]);
}
__device__ __forceinline__ void str_(void* p, size_t i, float v, bool f32) {
  if (f32) ((float*)p)[i] = v; else ((uint16_t*)p)[i] = f2b(v);
}

// ---------------- DPP 16-lane (row) reductions ----------------
template <int CTRL>
__device__ __forceinline__ float fdpp(float x) {
  int v = __builtin_amdgcn_mov_dpp(__builtin_bit_cast(int, x), CTRL, 0xf, 0xf, true);
  return __builtin_bit_cast(float, v);
}
__device__ __forceinline__ float row16_max(float x) {
  x = fmaxf(x, fdpp<0xB1>(x));
  x = fmaxf(x, fdpp<0x4E>(x));
  x = fmaxf(x, fdpp<0x124>(x));
  x = fmaxf(x, fdpp<0x128>(x));
  return x;
}
__device__ __forceinline__ float row16_sum(float x) {
  x += fdpp<0xB1>(x);
  x += fdpp<0x4E>(x);
  x += fdpp<0x124>(x);
  x += fdpp<0x128>(x);
  return x;
}

// XOR-swizzled byte offset into a 16x64 bf16 LDS tile (row stride 128 B) — attn P tile.
__device__ __forceinline__ int psw(int row, int col) {
  return (((row) << 7) + ((col) << 1)) ^ ((row & 7) << 4);
}

// ---------------- input dtype detector ----------------
__global__ void detect_kernel(const uint16_t* __restrict__ x, int* __restrict__ flag) {
  if (threadIdx.x == 0 && blockIdx.x == 0) {
    int sane = 0;
    for (int i = 0; i < 256; ++i) {
      uint16_t u = x[i];
      int e = (u >> 7) & 0xFF;
      if (u == 0 || (e >= 90 && e <= 141)) sane++;
    }
    *flag = (sane >= 240) ? 0 : 1;   // 0 = bf16, 1 = f32
  }
}

// ---------------- RoPE cos/sin table: [S_][32] ----------------
__global__ __launch_bounds__(256) void rope_table_kernel(float* __restrict__ cosT,
                                                         float* __restrict__ sinT) {
  int i = blockIdx.x * 256 + threadIdx.x;       // 65536 entries
  int s = i >> 5, d = i & 31;
  float ang = (float)s * powf(10000.0f, -(float)d * (1.0f / 32.0f));
  cosT[i] = cosf(ang);
  sinT[i] = sinf(ang);
}

// ---------------- transpose: in (K x N, in-dtype) -> out (N x K, bf16) ----------------
template <bool F32>
__device__ __forceinline__ void trans_body(const void* in, uint16_t* out, int K, int N,
                                           uint16_t (*tile)[33]) {
  int n0 = blockIdx.x * 32, k0 = blockIdx.y * 32;
  int tx = threadIdx.x & 31, ty = threadIdx.x >> 5;   // ty 0..7
#pragma unroll
  for (int i = 0; i < 32; i += 8) {
    size_t idx = (size_t)(k0 + ty + i) * N + n0 + tx;
    tile[ty + i][tx] = F32 ? f2b(((const float*)in)[idx]) : ((const uint16_t*)in)[idx];
  }
  __syncthreads();
#pragma unroll
  for (int i = 0; i < 32; i += 8) out[(size_t)(n0 + ty + i) * K + k0 + tx] = tile[tx][ty + i];
}
__global__ __launch_bounds__(256) void transpose_k(const void* __restrict__ in,
                                                   uint16_t* __restrict__ out,
                                                   int K, int N, const int* __restrict__ flag) {
  __shared__ uint16_t tile[32][33];
  if (*flag) trans_body<true>(in, out, K, N, tile);
  else       trans_body<false>(in, out, K, N, tile);
}

// ---------------- LayerNorm (one block per row, D_=1024); output always bf16 ----------------
template <bool F32>
__device__ __forceinline__ void ln_body(const void* x, const void* gamma, const void* beta,
                                        uint16_t* out, float* red) {
  const int row = blockIdx.x;
  const int t = threadIdx.x;
  float f[4], s1 = 0.f, s2 = 0.f;
#pragma unroll
  for (int i = 0; i < 4; i++) {
    f[i] = F32 ? ((const float*)x)[(size_t)row * D_ + t * 4 + i]
               : b2f(((const uint16_t*)x)[(size_t)row * D_ + t * 4 + i]);
    s1 += f[i]; s2 += f[i] * f[i];
  }
  for (int off = 1; off < 64; off <<= 1) { s1 += __shfl_xor(s1, off); s2 += __shfl_xor(s2, off); }
  int wave = t >> 6;
  if ((t & 63) == 0) { red[wave] = s1; red[4 + wave] = s2; }
  __syncthreads();
  s1 = red[0] + red[1] + red[2] + red[3];
  s2 = red[4] + red[5] + red[6] + red[7];
  float mean = s1 * (1.f / D_);
  float var = s2 * (1.f / D_) - mean * mean;
  float rstd = rsqrtf(var + 1e-5f);
  uint16_t ov[4];
#pragma unroll
  for (int i = 0; i < 4; i++) {
    float gv = F32 ? ((const float*)gamma)[t * 4 + i] : b2f(((const uint16_t*)gamma)[t * 4 + i]);
    float bv = F32 ? ((const float*)beta)[t * 4 + i]  : b2f(((const uint16_t*)beta)[t * 4 + i]);
    ov[i] = f2b((f[i] - mean) * rstd * gv + bv);
  }
  *(uint64_t*)(out + (size_t)row * D_ + t * 4) = *(uint64_t*)ov;
}
__global__ __launch_bounds__(256) void ln_kernel(const void* __restrict__ x,
                                                 const void* __restrict__ gamma,
                                                 const void* __restrict__ beta,
                                                 uint16_t* __restrict__ out,
                                                 const int* __restrict__ flag) {
  __shared__ float red[8];
  if (*flag) ln_body<true>(x, gamma, beta, out, red);
  else       ln_body<false>(x, gamma, beta, out, red);
}

// ---------------- GEMM: C(MxN) = A(MxK) @ Bt(NxK)^T, fused epilogues ----------------
// R13 (kept, measured −14us): EPI_QKV merged launch over contiguous wqT|wkT|wvT
// (Bt[1536][1024], block-uniform epilogue branch on bn); GELU/ACC/RES use 2x2 wave
// decomposition (1.0 ds_read/MFMA vs banded 1.25); ROPE-shaped keep banded (needs
// d,d+32 in-wave). Counted-vmcnt pipeline (R12) + both-sides XOR swizzle (rule #21).
enum { EPI_ROPE = 1, EPI_TRANSV = 2, EPI_GELU = 3, EPI_RES = 4, EPI_ACC = 5, EPI_QKV = 6 };

template <int EPI>
__global__ __launch_bounds__(256) void gemm_bt(const uint16_t* __restrict__ A, int lda,
                                               const uint16_t* __restrict__ Bt, int ldb,
                                               void* __restrict__ C, int ldc,
                                               int M, int N, int K,
                                               const float* __restrict__ cosT,
                                               const float* __restrict__ sinT,
                                               const void* __restrict__ bias, int bias_off,
                                               const void* __restrict__ res,
                                               const int* __restrict__ flag,
                                               void* __restrict__ C2, void* __restrict__ C3) {
  constexpr bool BANDED = (EPI == EPI_ROPE || EPI == EPI_TRANSV || EPI == EPI_QKV);
  __shared__ __align__(16) uint16_t As[2][64 * 64];    // 16 KB
  __shared__ __align__(16) uint16_t Bs[2][64 * 64];    // 16 KB
  const int tid = threadIdx.x;
  const int wave = tid >> 6, lane = tid & 63;
  const int quad = lane >> 4, l15 = lane & 15;
  const int wm = wave >> 1, wn = wave & 1;             // 2x2 path only
  const int bm = blockIdx.x * 64, bn = blockIdx.y * 64;
  const bool f32 = flag ? (*flag != 0) : false;

  const int arow = tid >> 3;                 // 0..31
  const int gcol = (tid & 7) ^ (arow & 7);   // pre-swizzled 16B-slot (involution, rule #21)
  const uint16_t* apt = A + (size_t)(bm + arow) * lda + gcol * 8;
  const uint16_t* bpt = Bt + (size_t)(bn + arow) * ldb + gcol * 8;
  const int woff = wave * 512;               // wave base within a 32-row issue segment

  f32x4 acc[4];                              // banded: 4 col-frags; 2x2: [mi*2+ni]
  f32x4 zero = {0.f, 0.f, 0.f, 0.f};
#pragma unroll
  for (int j = 0; j < 4; j++) acc[j] = zero;

  auto stage = [&](int buf, int it) {
    const uint16_t* a = apt + it * 64;
    const uint16_t* b = bpt + it * 64;
    gl16(a,                     &As[buf][woff]);
    gl16(a + (size_t)32 * lda,  &As[buf][2048 + woff]);
    gl16(b,                     &Bs[buf][woff]);
    gl16(b + (size_t)32 * ldb,  &Bs[buf][2048 + woff]);
  };

  const int NIT = K >> 6;
  stage(0, 0);                      // 4 loads in flight; awaited by iter 0's vmcnt
  int cur = 0;
  for (int it = 0; it < NIT; ++it) {
    stage(cur ^ 1, (it + 1 < NIT) ? (it + 1) : it);   // 4 more; clamp keeps count uniform
    asm volatile("s_waitcnt vmcnt(4)" ::: "memory");  // tile it landed; it+1 in flight
    __builtin_amdgcn_s_barrier();                     // all waves' tile-it writes visible
    asm volatile("" ::: "memory");
    if constexpr (BANDED) {
      frag8 af[2], bfv[4][2];
#pragma unroll
      for (int ks = 0; ks < 2; ++ks) {
        int row = wave * 16 + l15;                 // row&7 == l15&7
        int c16 = (ks * 4 + quad) ^ (l15 & 7);
        af[ks] = *(const frag8*)&As[cur][row * 64 + c16 * 8];
      }
#pragma unroll
      for (int ni = 0; ni < 4; ++ni)
#pragma unroll
        for (int ks = 0; ks < 2; ++ks) {
          int row = ni * 16 + l15;
          int c16 = (ks * 4 + quad) ^ (l15 & 7);
          bfv[ni][ks] = *(const frag8*)&Bs[cur][row * 64 + c16 * 8];
        }
#pragma unroll
      for (int ks = 0; ks < 2; ++ks)
#pragma unroll
        for (int ni = 0; ni < 4; ++ni)
          acc[ni] = __builtin_amdgcn_mfma_f32_16x16x32_bf16(af[ks], bfv[ni][ks], acc[ni], 0, 0, 0);
    } else {
      frag8 af2[2][2], bf2[2][2];
#pragma unroll
      for (int mi = 0; mi < 2; ++mi)
#pragma unroll
        for (int ks = 0; ks < 2; ++ks) {
          int row = wm * 32 + mi * 16 + l15;       // row&7 == l15&7
          int c16 = (ks * 4 + quad) ^ (l15 & 7);
          af2[mi][ks] = *(const frag8*)&As[cur][row * 64 + c16 * 8];
        }
#pragma unroll
      for (int ni = 0; ni < 2; ++ni)
#pragma unroll
        for (int ks = 0; ks < 2; ++ks) {
          int row = wn * 32 + ni * 16 + l15;
          int c16 = (ks * 4 + quad) ^ (l15 & 7);
          bf2[ni][ks] = *(const frag8*)&Bs[cur][row * 64 + c16 * 8];
        }
#pragma unroll
      for (int ks = 0; ks < 2; ++ks)
#pragma unroll
        for (int mi = 0; mi < 2; ++mi)
#pragma unroll
          for (int ni = 0; ni < 2; ++ni)
            acc[mi * 2 + ni] = __builtin_amdgcn_mfma_f32_16x16x32_bf16(af2[mi][ks], bf2[ni][ks],
                                                                       acc[mi * 2 + ni], 0, 0, 0);
    }
    asm volatile("s_waitcnt lgkmcnt(0)" ::: "memory");  // this wave's reads retired
    __builtin_amdgcn_s_barrier();                       // all waves done with buf[cur]
    cur ^= 1;
  }

  if constexpr (EPI == EPI_ROPE || EPI == EPI_QKV) {
    const int row0 = bm + wave * 16 + quad * 4;
    if (EPI == EPI_ROPE || bn < 1024) {
      // Q (or plain ROPE): -> C, ldc
#pragma unroll
      for (int r = 0; r < 4; ++r) {
        int row = row0 + r;
        int s = row & (S_ - 1);
#pragma unroll
        for (int ni = 0; ni < 2; ++ni) {
          int d = ni * 16 + l15;
          float c = cosT[s * 32 + d], sn = sinT[s * 32 + d];
          float x1 = acc[ni][r], x2 = acc[ni + 2][r];
          size_t base = (size_t)row * ldc + bn + ni * 16 + l15;
          ((uint16_t*)C)[base] = f2b(x1 * c - x2 * sn);
          ((uint16_t*)C)[base + 32] = f2b(x1 * sn + x2 * c);
        }
      }
    } else if (bn < 1280) {
      // K + RoPE -> C2 (kbuf), ldc 256
      uint16_t* kb = (uint16_t*)C2;
#pragma unroll
      for (int r = 0; r < 4; ++r) {
        int row = row0 + r;
        int s = row & (S_ - 1);
#pragma unroll
        for (int ni = 0; ni < 2; ++ni) {
          int d = ni * 16 + l15;
          float c = cosT[s * 32 + d], sn = sinT[s * 32 + d];
          float x1 = acc[ni][r], x2 = acc[ni + 2][r];
          size_t base = (size_t)row * 256 + (bn - 1024) + ni * 16 + l15;
          kb[base] = f2b(x1 * c - x2 * sn);
          kb[base + 32] = f2b(x1 * sn + x2 * c);
        }
      }
    } else {
      // V -> C3 (vtb), transposed [(b,kvh,d)][s]
      uint16_t* vb = (uint16_t*)C3;
#pragma unroll
      for (int ni = 0; ni < 4; ++ni)
#pragma unroll
        for (int r = 0; r < 4; ++r) {
          int row = row0 + r;
          int col3 = (bn - 1280) + ni * 16 + l15;
          int b = row >> 11, s = row & (S_ - 1);
          int kvh = col3 >> 6, d = col3 & 63;
          vb[(size_t)((b * HKV_ + kvh) * HD_ + d) * S_ + s] = f2b(acc[ni][r]);
        }
    }
  } else if constexpr (EPI == EPI_TRANSV) {
    const int row0 = bm + wave * 16 + quad * 4;
#pragma unroll
    for (int ni = 0; ni < 4; ++ni)
#pragma unroll
      for (int r = 0; r < 4; ++r) {
        int row = row0 + r;
        int col = bn + ni * 16 + l15;
        int b = row >> 11, s = row & (S_ - 1);
        int kvh = col >> 6, d = col & 63;
        ((uint16_t*)C)[(size_t)((b * HKV_ + kvh) * HD_ + d) * S_ + s] = f2b(acc[ni][r]);
      }
  } else {
    // 2x2 wave layout: wave covers rows wm*32..+31, cols wn*32..+31
    const int row0 = bm + wm * 32 + quad * 4;
#pragma unroll
    for (int mi = 0; mi < 2; ++mi)
#pragma unroll
      for (int ni = 0; ni < 2; ++ni) {
        int col = bn + wn * 32 + ni * 16 + l15;
#pragma unroll
        for (int r = 0; r < 4; ++r) {
          int row = row0 + mi * 16 + r;
          float v = acc[mi * 2 + ni][r];
          if constexpr (EPI == EPI_GELU) {
            v += ldr(bias, bias_off + col, f32);
            float z = 0.7978845608028654f * (v + 0.044715f * v * v * v);
            z = fminf(fmaxf(z, -15.f), 15.f);
            float e = __expf(-2.f * z);
            v = 0.5f * v * (1.f + (1.f - e) / (1.f + e));   // tanh gelu (jax default)
            ((uint16_t*)C)[(size_t)row * ldc + col] = f2b(v);
          } else if constexpr (EPI == EPI_RES) {
            v += ldr(res, (size_t)row * ldc + col, f32);
            str_(C, (size_t)row * ldc + col, v, f32);
          } else if constexpr (EPI == EPI_ACC) {
            if (bias) v += ldr(bias, bias_off + col, f32);
            v += ldr(C, (size_t)row * ldc + col, f32);   // accumulate (residual lives here)
            str_(C, (size_t)row * ldc + col, v, f32);
          }
        }
      }
  }
}

// ---------------- Flash attention ----------------
// v6 REVERT (R14): v7's "VALU diet" regressed (74.3us, VALUBusy 44->57%): grow-skip
// branch almost always taken early (pure overhead) and exp2f lowered worse than
// __expf. v6 is the most-replicated number in the session (63.2-63.9us across
// R9/R10/R11). Block-cooperative GQA + qt pairing; K/V staged once per block via
// gl16 double-buffered LDS; both-sides XOR swizzle; nt sum == 33 every block.
__global__ __launch_bounds__(256, 4) void attn_kernel(const uint16_t* __restrict__ q,
                                                      const uint16_t* __restrict__ k,
                                                      const uint16_t* __restrict__ vt,
                                                      uint16_t* __restrict__ o) {
  __shared__ __align__(16) uint16_t Ks[2][64 * 64];   // [key][dim] swizzled, 16 KB
  __shared__ __align__(16) uint16_t Vs[2][64 * 64];   // [d][key] swizzled, 16 KB
  __shared__ __align__(16) uint16_t Plds[4][16 * 64]; // per-wave P, 8 KB
  const int tid = threadIdx.x;
  const int wave = tid >> 6, lane = tid & 63;
  const int quad = lane >> 4, l15 = lane & 15;
  const int bid = blockIdx.x;                 // 0..511
  const int m = bid & 63;
  const int g = (bid >> 6) & 3;
  const int b = bid >> 8;
  const int h = g + 4 * wave;                 // this wave's q head (shares kv head g)

  const uint16_t* kbase = k + (size_t)(b * S_) * (HKV_ * HD_) + g * HD_;
  const uint16_t* vbase = vt + (size_t)((b * HKV_ + g) * HD_) * S_;
  f32x4 zero = {0.f, 0.f, 0.f, 0.f};

  const int arow = tid >> 3;                  // 0..31
  const int gcol = (tid & 7) ^ (arow & 7);
  const int woff = wave * 512;                // dest: wave*1024B + lane*16B (linear)
  uint16_t* pw = Plds[wave];

  auto stage = [&](int buf, int t) {
    const int kt = t << 6;
    gl16(kbase + (size_t)(kt + arow) * (HKV_ * HD_) + gcol * 8,      &Ks[buf][woff]);
    gl16(kbase + (size_t)(kt + 32 + arow) * (HKV_ * HD_) + gcol * 8, &Ks[buf][2048 + woff]);
    gl16(vbase + (size_t)arow * S_ + kt + gcol * 8,                  &Vs[buf][woff]);
    gl16(vbase + (size_t)(arow + 32) * S_ + kt + gcol * 8,           &Vs[buf][2048 + woff]);
  };

  int cur = 0;
  for (int seg = 0; seg < 2; ++seg) {
    const int qt = seg ? (127 - m) : m;       // nt(m)+nt(127-m) == 33, every block
    const int q0 = qt * 16;

    const uint16_t* qbase = q + (size_t)(b * S_ + q0 + l15) * D_ + h * HD_ + quad * 8;
    frag8 qa0 = *(const frag8*)qbase;         // Q[m=l15][d=quad*8..+7]
    frag8 qa1 = *(const frag8*)(qbase + 32);  // d+32

    f32x4 oacc[4];
#pragma unroll
    for (int i = 0; i < 4; i++) oacc[i] = zero;
    float m_i[4] = {-1e30f, -1e30f, -1e30f, -1e30f};
    float l_i[4] = {0.f, 0.f, 0.f, 0.f};

    const int nt = (q0 + 16 + 63) >> 6;       // same for all 4 waves of the block
    stage(cur, 0);
    __syncthreads();                          // vmcnt(0) at barrier: tile 0 staged
    for (int t = 0; t < nt; ++t) {
      const int kt = t << 6;
      if (t + 1 < nt) stage(cur ^ 1, t + 1);  // in flight under compute below

      // QK^T from LDS (swizzled read: slot c16 = logical ^ (row&7), row&7 == l15&7)
      f32x4 sc[4];
#pragma unroll
      for (int f = 0; f < 4; ++f) {
        const int row = 16 * f + l15;
        frag8 kb0 = *(const frag8*)&Ks[cur][row * 64 + ((quad ^ (l15 & 7)) * 8)];
        frag8 kb1 = *(const frag8*)&Ks[cur][row * 64 + (((quad + 4) ^ (l15 & 7)) * 8)];
        f32x4 c = zero;
        c = __builtin_amdgcn_mfma_f32_16x16x32_bf16(qa0, kb0, c, 0, 0, 0);
        c = __builtin_amdgcn_mfma_f32_16x16x32_bf16(qa1, kb1, c, 0, 0, 0);
        sc[f] = c;
      }
      const bool needmask = (kt + 63 > q0);
      float p[4][4];   // [fragment f][row r]; score row = q0+quad*4+r, key = kt+16f+l15
#pragma unroll
      for (int f = 0; f < 4; ++f)
#pragma unroll
        for (int r = 0; r < 4; ++r) p[f][r] = sc[f][r] * 0.125f;
      if (needmask) {
#pragma unroll
        for (int r = 0; r < 4; ++r) {
          int qq = q0 + quad * 4 + r;
#pragma unroll
          for (int f = 0; f < 4; ++f)
            if (kt + 16 * f + l15 > qq) p[f][r] = -1e30f;
        }
      }
      float alpha[4];
#pragma unroll
      for (int r = 0; r < 4; ++r) {
        float rm = fmaxf(fmaxf(p[0][r], p[1][r]), fmaxf(p[2][r], p[3][r]));
        rm = row16_max(rm);                        // DPP, VALU-speed
        float mn = fmaxf(m_i[r], rm);
        alpha[r] = __expf(m_i[r] - mn);
        m_i[r] = mn;
        float rs = 0.f;
#pragma unroll
        for (int f = 0; f < 4; ++f) { p[f][r] = __expf(p[f][r] - mn); rs += p[f][r]; }
        rs = row16_sum(rs);                        // DPP
        l_i[r] = l_i[r] * alpha[r] + rs;
      }
      // C-layout P -> A-layout via per-wave swizzled LDS round trip (row=q, col=key)
#pragma unroll
      for (int r = 0; r < 4; ++r) {
        int row = quad * 4 + r;
#pragma unroll
        for (int f = 0; f < 4; ++f)
          *(uint16_t*)((char*)pw + psw(row, f * 16 + l15)) = f2b(p[f][r]);
      }
      asm volatile("s_waitcnt lgkmcnt(0)" ::: "memory");
      frag8 pa0 = *(const frag8*)((const char*)pw + psw(l15, quad * 8));        // keys kt..+31
      frag8 pa1 = *(const frag8*)((const char*)pw + psw(l15, 32 + quad * 8));   // keys kt+32..+63
#pragma unroll
      for (int d4 = 0; d4 < 4; ++d4) {
        const int row = d4 * 16 + l15;
        frag8 vb0 = *(const frag8*)&Vs[cur][row * 64 + ((quad ^ (l15 & 7)) * 8)];
        frag8 vb1 = *(const frag8*)&Vs[cur][row * 64 + (((quad + 4) ^ (l15 & 7)) * 8)];
        f32x4 t4 = oacc[d4];
#pragma unroll
        for (int r = 0; r < 4; ++r) t4[r] *= alpha[r];
        t4 = __builtin_amdgcn_mfma_f32_16x16x32_bf16(pa0, vb0, t4, 0, 0, 0);
        t4 = __builtin_amdgcn_mfma_f32_16x16x32_bf16(pa1, vb1, t4, 0, 0, 0);
        oacc[d4] = t4;
      }
      __syncthreads();   // all waves done reading Ks/Vs[cur]; stage(t+1) drained (vmcnt0)
      cur ^= 1;
    }

#pragma unroll
    for (int d4 = 0; d4 < 4; ++d4)
#pragma unroll
      for (int r = 0; r < 4; ++r) {
        int row = b * S_ + q0 + quad * 4 + r;
        int col = h * HD_ + d4 * 16 + l15;
        o[(size_t)row * D_ + col] = f2b(oacc[d4][r] / l_i[r]);
      }
  }
}

// ---------------- launcher ----------------
extern "C" void kernel_launch(void* const* d_in, const int* in_sizes, int n_in,
                              void* d_out, int out_size, void* d_ws, size_t ws_size,
                              hipStream_t stream) {
  const void* x    = d_in[0];
  const void* wq   = d_in[2];
  const void* wk   = d_in[3];
  const void* wv   = d_in[4];
  const void* wo   = d_in[5];
  const void* ln1g = d_in[6];
  const void* ln1b = d_in[7];
  const void* ln2g = d_in[8];
  const void* ln2b = d_in[9];
  const void* w1   = d_in[10];
  const void* b1   = d_in[11];
  const void* w2   = d_in[12];
  const void* b2   = d_in[13];

  char* w = (char*)d_ws;
  // layout (bytes), total ~37.5 MB. wqT/wkT/wvT are deliberately CONTIGUOUS:
  // together they form Bt[1536][1024] for the merged QKV GEMM.
  int*      flag = (int*)w;                            // 4 B (padded to 4 KB)
  float*    cosT = (float*)(w + 4096);                 // 256 KB
  float*    sinT = (float*)(w + 266240);               // 256 KB
  uint16_t* wqT  = (uint16_t*)(w + 528384);            // 2 MB
  uint16_t* wkT  = (uint16_t*)(w + 2625536);           // 512 KB (= wqT + 2MB)
  uint16_t* wvT  = (uint16_t*)(w + 3149824);           // 512 KB (= wkT + 512KB)
  uint16_t* woT  = (uint16_t*)(w + 3674112);           // 2 MB
  uint16_t* hbuf = (uint16_t*)(w + 5771264);           // 8 MB
  uint16_t* qbuf = (uint16_t*)(w + 14159872);          // 8 MB   } w1T after attn
  uint16_t* kbuf = (uint16_t*)(w + 22548480);          // 2 MB   } w2T after RES gemm
  uint16_t* vtb  = (uint16_t*)(w + 24645632);          // 2 MB   }
  uint16_t* obuf = (uint16_t*)(w + 26742784);          // 8 MB   }
  uint16_t* w1T  = (uint16_t*)(w + 14159872);          // 8 MB (over dead qbuf)
  uint16_t* w2T  = (uint16_t*)(w + 22548480);          // 8 MB, ends at 30937088
  uint16_t* hidq = (uint16_t*)(w + 30937088);          // 8 MB, AFTER w2T

  detect_kernel<<<dim3(1), dim3(64), 0, stream>>>((const uint16_t*)x, flag);
  rope_table_kernel<<<dim3(256), dim3(256), 0, stream>>>(cosT, sinT);

  transpose_k<<<dim3(32, 32), dim3(256), 0, stream>>>(wq, wqT, 1024, 1024, flag);
  transpose_k<<<dim3(8, 32), dim3(256), 0, stream>>>(wk, wkT, 1024, 256, flag);
  transpose_k<<<dim3(8, 32), dim3(256), 0, stream>>>(wv, wvT, 1024, 256, flag);
  transpose_k<<<dim3(32, 32), dim3(256), 0, stream>>>(wo, woT, 1024, 1024, flag);

  ln_kernel<<<dim3(4096), dim3(256), 0, stream>>>(x, ln1g, ln1b, hbuf, flag);

  // merged QKV: N=1536 over contiguous wqT|wkT|wvT; epilogue branches on bn
  gemm_bt<EPI_QKV><<<dim3(64, 24), dim3(256), 0, stream>>>(hbuf, 1024, wqT, 1024, qbuf, 1024,
      4096, 1536, 1024, cosT, sinT, nullptr, 0, nullptr, nullptr, kbuf, vtb);

  attn_kernel<<<dim3(512), dim3(256), 0, stream>>>(qbuf, kbuf, vtb, obuf);

  transpose_k<<<dim3(128, 32), dim3(256), 0, stream>>>(w1, w1T, 1024, 4096, flag);

  gemm_bt<EPI_RES><<<dim3(64, 16), dim3(256), 0, stream>>>(obuf, 1024, woT, 1024, d_out, 1024,
      4096, 1024, 1024, nullptr, nullptr, nullptr, 0, x, flag, nullptr, nullptr);

  transpose_k<<<dim3(32, 128), dim3(256), 0, stream>>>(w2, w2T, 4096, 1024, flag);

  ln_kernel<<<dim3(4096), dim3(256), 0, stream>>>(d_out, ln2g, ln2b, hbuf, flag);

  // MLP in 4 P-chunks: hidq = gelu(hbuf @ w1T_chunk + b1_chunk); d_out += hidq @ w2T_chunk
  for (int j = 0; j < 4; ++j) {
    const uint16_t* w1c = w1T + (size_t)j * 1024 * 1024;
    const uint16_t* w2c = w2T + (size_t)j * 1024;
    const void* bb = (j == 0) ? b2 : nullptr;
    gemm_bt<EPI_GELU><<<dim3(64, 16), dim3(256), 0, stream>>>(hbuf, 1024, w1c, 1024, hidq, 1024,
        4096, 1024, 1024, nullptr, nullptr, b1, j * 1024, nullptr, flag, nullptr, nullptr);
    gemm_bt<EPI_ACC><<<dim3(64, 16), dim3(256), 0, stream>>>(hidq, 1024, w2c, 4096, d_out, 1024,
        4096, 1024, 1024, nullptr, nullptr, bb, 0, nullptr, flag, nullptr, nullptr);
  }
}

// Round 15
// 422.645 us; speedup vs baseline: 1.0245x; 1.0245x over previous
//
#include <hip/hip_runtime.h>
#include <cstdint>
#include <cstddef>

#define B_   2
#define S_   2048
#define D_   1024
#define HQ_  16
#define HKV_ 4
#define HD_  64
#define P_   4096

using frag8 = __attribute__((ext_vector_type(8))) short;   // 8 bf16 (4 VGPRs)
using f32x4 = __attribute__((ext_vector_type(4))) float;   // 4 fp32 acc

__device__ __forceinline__ uint16_t f2b(float f) {
  uint32_t u = __builtin_bit_cast(uint32_t, f);
  u += 0x7fffu + ((u >> 16) & 1u);          // RNE
  return (uint16_t)(u >> 16);
}
__device__ __forceinline__ float b2f(uint16_t h) {
  return __builtin_bit_cast(float, (uint32_t)h << 16);
}

// async global->LDS, 16B per lane. LDS dest = wave-uniform base + lane*16 (HW rule).
__device__ __forceinline__ void gl16(const uint16_t* g, uint16_t* l) {
  __builtin_amdgcn_global_load_lds(
      (const __attribute__((address_space(1))) void*)g,
      (__attribute__((address_space(3))) void*)l, 16, 0, 0);
}

// runtime-dtype scalar load/store (f32: buffer is float; else bf16)
__device__ __forceinline__ float ldr(const void* p, size_t i, bool f32) {
  return f32 ? ((const float*)p)[i] : b2f(((const uint16_t*)p)[i]);
}
__device__ __forceinline__ void str_(void* p, size_t i, float v, bool f32) {
  if (f32) ((float*)p)[i] = v; else ((uint16_t*)p)[i] = f2b(v);
}

// ---------------- DPP 16-lane (row) reductions ----------------
template <int CTRL>
__device__ __forceinline__ float fdpp(float x) {
  int v = __builtin_amdgcn_mov_dpp(__builtin_bit_cast(int, x), CTRL, 0xf, 0xf, true);
  return __builtin_bit_cast(float, v);
}
__device__ __forceinline__ float row16_max(float x) {
  x = fmaxf(x, fdpp<0xB1>(x));
  x = fmaxf(x, fdpp<0x4E>(x));
  x = fmaxf(x, fdpp<0x124>(x));
  x = fmaxf(x, fdpp<0x128>(x));
  return x;
}
__device__ __forceinline__ float row16_sum(float x) {
  x += fdpp<0xB1>(x);
  x += fdpp<0x4E>(x);
  x += fdpp<0x124>(x);
  x += fdpp<0x128>(x);
  return x;
}

// XOR-swizzled byte offset into a 16x64 bf16 LDS tile (row stride 128 B) — attn P tile.
__device__ __forceinline__ int psw(int row, int col) {
  return (((row) << 7) + ((col) << 1)) ^ ((row & 7) << 4);
}

// ---------------- input dtype detector ----------------
__global__ void detect_kernel(const uint16_t* __restrict__ x, int* __restrict__ flag) {
  if (threadIdx.x == 0 && blockIdx.x == 0) {
    int sane = 0;
    for (int i = 0; i < 256; ++i) {
      uint16_t u = x[i];
      int e = (u >> 7) & 0xFF;
      if (u == 0 || (e >= 90 && e <= 141)) sane++;
    }
    *flag = (sane >= 240) ? 0 : 1;   // 0 = bf16, 1 = f32
  }
}

// ---------------- RoPE cos/sin table: [S_][32] ----------------
__global__ __launch_bounds__(256) void rope_table_kernel(float* __restrict__ cosT,
                                                         float* __restrict__ sinT) {
  int i = blockIdx.x * 256 + threadIdx.x;       // 65536 entries
  int s = i >> 5, d = i & 31;
  float ang = (float)s * powf(10000.0f, -(float)d * (1.0f / 32.0f));
  cosT[i] = cosf(ang);
  sinT[i] = sinf(ang);
}

// ---------------- transpose: in (K x N, in-dtype) -> out (N x K, bf16) ----------------
template <bool F32>
__device__ __forceinline__ void trans_body(const void* in, uint16_t* out, int K, int N,
                                           uint16_t (*tile)[33]) {
  int n0 = blockIdx.x * 32, k0 = blockIdx.y * 32;
  int tx = threadIdx.x & 31, ty = threadIdx.x >> 5;   // ty 0..7
#pragma unroll
  for (int i = 0; i < 32; i += 8) {
    size_t idx = (size_t)(k0 + ty + i) * N + n0 + tx;
    tile[ty + i][tx] = F32 ? f2b(((const float*)in)[idx]) : ((const uint16_t*)in)[idx];
  }
  __syncthreads();
#pragma unroll
  for (int i = 0; i < 32; i += 8) out[(size_t)(n0 + ty + i) * K + k0 + tx] = tile[tx][ty + i];
}
__global__ __launch_bounds__(256) void transpose_k(const void* __restrict__ in,
                                                   uint16_t* __restrict__ out,
                                                   int K, int N, const int* __restrict__ flag) {
  __shared__ uint16_t tile[32][33];
  if (*flag) trans_body<true>(in, out, K, N, tile);
  else       trans_body<false>(in, out, K, N, tile);
}

// ---------------- LayerNorm (one block per row, D_=1024); output always bf16 ----------------
template <bool F32>
__device__ __forceinline__ void ln_body(const void* x, const void* gamma, const void* beta,
                                        uint16_t* out, float* red) {
  const int row = blockIdx.x;
  const int t = threadIdx.x;
  float f[4], s1 = 0.f, s2 = 0.f;
#pragma unroll
  for (int i = 0; i < 4; i++) {
    f[i] = F32 ? ((const float*)x)[(size_t)row * D_ + t * 4 + i]
               : b2f(((const uint16_t*)x)[(size_t)row * D_ + t * 4 + i]);
    s1 += f[i]; s2 += f[i] * f[i];
  }
  for (int off = 1; off < 64; off <<= 1) { s1 += __shfl_xor(s1, off); s2 += __shfl_xor(s2, off); }
  int wave = t >> 6;
  if ((t & 63) == 0) { red[wave] = s1; red[4 + wave] = s2; }
  __syncthreads();
  s1 = red[0] + red[1] + red[2] + red[3];
  s2 = red[4] + red[5] + red[6] + red[7];
  float mean = s1 * (1.f / D_);
  float var = s2 * (1.f / D_) - mean * mean;
  float rstd = rsqrtf(var + 1e-5f);
  uint16_t ov[4];
#pragma unroll
  for (int i = 0; i < 4; i++) {
    float gv = F32 ? ((const float*)gamma)[t * 4 + i] : b2f(((const uint16_t*)gamma)[t * 4 + i]);
    float bv = F32 ? ((const float*)beta)[t * 4 + i]  : b2f(((const uint16_t*)beta)[t * 4 + i]);
    ov[i] = f2b((f[i] - mean) * rstd * gv + bv);
  }
  *(uint64_t*)(out + (size_t)row * D_ + t * 4) = *(uint64_t*)ov;
}
__global__ __launch_bounds__(256) void ln_kernel(const void* __restrict__ x,
                                                 const void* __restrict__ gamma,
                                                 const void* __restrict__ beta,
                                                 uint16_t* __restrict__ out,
                                                 const int* __restrict__ flag) {
  __shared__ float red[8];
  if (*flag) ln_body<true>(x, gamma, beta, out, red);
  else       ln_body<false>(x, gamma, beta, out, red);
}

// ---------------- GEMM: C(MxN) = A(MxK) @ Bt(NxK)^T, fused epilogues ----------------
// R15: + T1 XCD-chunked block swizzle. Default x-fastest dispatch round-robins
// consecutive blocks across the 8 XCDs -> an XCD's blocks scatter over all bm and
// every A-panel read streams from L3 (~600cy) instead of its own L2 (~200cy).
// Remap so each XCD owns a contiguous bm-slab x all bn: A-slab (gridDim.x/8)x128KB
// = 1MB + B 2MB both fit the 4MB per-XCD L2. Bijective for gridDim.x%8==0 (all
// launches use gridDim.x=64). R13 geometry (QKV merge, 2x2/banded) + R12
// counted-vmcnt kept verbatim.
enum { EPI_ROPE = 1, EPI_TRANSV = 2, EPI_GELU = 3, EPI_RES = 4, EPI_ACC = 5, EPI_QKV = 6 };

template <int EPI>
__global__ __launch_bounds__(256) void gemm_bt(const uint16_t* __restrict__ A, int lda,
                                               const uint16_t* __restrict__ Bt, int ldb,
                                               void* __restrict__ C, int ldc,
                                               int M, int N, int K,
                                               const float* __restrict__ cosT,
                                               const float* __restrict__ sinT,
                                               const void* __restrict__ bias, int bias_off,
                                               const void* __restrict__ res,
                                               const int* __restrict__ flag,
                                               void* __restrict__ C2, void* __restrict__ C3) {
  constexpr bool BANDED = (EPI == EPI_ROPE || EPI == EPI_TRANSV || EPI == EPI_QKV);
  __shared__ __align__(16) uint16_t As[2][64 * 64];    // 16 KB
  __shared__ __align__(16) uint16_t Bs[2][64 * 64];    // 16 KB
  const int tid = threadIdx.x;
  const int wave = tid >> 6, lane = tid & 63;
  const int quad = lane >> 4, l15 = lane & 15;
  const int wm = wave >> 1, wn = wave & 1;             // 2x2 path only

  // T1: XCD-chunked bijective remap (xcd = orig%8 preserved -> HW round-robin gives
  // each XCD a contiguous local range; local maps bm-fastest within a bm-slab).
  const int orig = blockIdx.y * gridDim.x + blockIdx.x;
  const int xcd = orig & 7, local = orig >> 3;
  const int gx8 = gridDim.x >> 3;                      // 8 for gridDim.x=64
  const int bm = (xcd * gx8 + (local % gx8)) * 64;
  const int bn = (local / gx8) * 64;
  const bool f32 = flag ? (*flag != 0) : false;

  const int arow = tid >> 3;                 // 0..31
  const int gcol = (tid & 7) ^ (arow & 7);   // pre-swizzled 16B-slot (involution, rule #21)
  const uint16_t* apt = A + (size_t)(bm + arow) * lda + gcol * 8;
  const uint16_t* bpt = Bt + (size_t)(bn + arow) * ldb + gcol * 8;
  const int woff = wave * 512;               // wave base within a 32-row issue segment

  f32x4 acc[4];                              // banded: 4 col-frags; 2x2: [mi*2+ni]
  f32x4 zero = {0.f, 0.f, 0.f, 0.f};
#pragma unroll
  for (int j = 0; j < 4; j++) acc[j] = zero;

  auto stage = [&](int buf, int it) {
    const uint16_t* a = apt + it * 64;
    const uint16_t* b = bpt + it * 64;
    gl16(a,                     &As[buf][woff]);
    gl16(a + (size_t)32 * lda,  &As[buf][2048 + woff]);
    gl16(b,                     &Bs[buf][woff]);
    gl16(b + (size_t)32 * ldb,  &Bs[buf][2048 + woff]);
  };

  const int NIT = K >> 6;
  stage(0, 0);                      // 4 loads in flight; awaited by iter 0's vmcnt
  int cur = 0;
  for (int it = 0; it < NIT; ++it) {
    stage(cur ^ 1, (it + 1 < NIT) ? (it + 1) : it);   // 4 more; clamp keeps count uniform
    asm volatile("s_waitcnt vmcnt(4)" ::: "memory");  // tile it landed; it+1 in flight
    __builtin_amdgcn_s_barrier();                     // all waves' tile-it writes visible
    asm volatile("" ::: "memory");
    if constexpr (BANDED) {
      frag8 af[2], bfv[4][2];
#pragma unroll
      for (int ks = 0; ks < 2; ++ks) {
        int row = wave * 16 + l15;                 // row&7 == l15&7
        int c16 = (ks * 4 + quad) ^ (l15 & 7);
        af[ks] = *(const frag8*)&As[cur][row * 64 + c16 * 8];
      }
#pragma unroll
      for (int ni = 0; ni < 4; ++ni)
#pragma unroll
        for (int ks = 0; ks < 2; ++ks) {
          int row = ni * 16 + l15;
          int c16 = (ks * 4 + quad) ^ (l15 & 7);
          bfv[ni][ks] = *(const frag8*)&Bs[cur][row * 64 + c16 * 8];
        }
#pragma unroll
      for (int ks = 0; ks < 2; ++ks)
#pragma unroll
        for (int ni = 0; ni < 4; ++ni)
          acc[ni] = __builtin_amdgcn_mfma_f32_16x16x32_bf16(af[ks], bfv[ni][ks], acc[ni], 0, 0, 0);
    } else {
      frag8 af2[2][2], bf2[2][2];
#pragma unroll
      for (int mi = 0; mi < 2; ++mi)
#pragma unroll
        for (int ks = 0; ks < 2; ++ks) {
          int row = wm * 32 + mi * 16 + l15;       // row&7 == l15&7
          int c16 = (ks * 4 + quad) ^ (l15 & 7);
          af2[mi][ks] = *(const frag8*)&As[cur][row * 64 + c16 * 8];
        }
#pragma unroll
      for (int ni = 0; ni < 2; ++ni)
#pragma unroll
        for (int ks = 0; ks < 2; ++ks) {
          int row = wn * 32 + ni * 16 + l15;
          int c16 = (ks * 4 + quad) ^ (l15 & 7);
          bf2[ni][ks] = *(const frag8*)&Bs[cur][row * 64 + c16 * 8];
        }
#pragma unroll
      for (int ks = 0; ks < 2; ++ks)
#pragma unroll
        for (int mi = 0; mi < 2; ++mi)
#pragma unroll
          for (int ni = 0; ni < 2; ++ni)
            acc[mi * 2 + ni] = __builtin_amdgcn_mfma_f32_16x16x32_bf16(af2[mi][ks], bf2[ni][ks],
                                                                       acc[mi * 2 + ni], 0, 0, 0);
    }
    asm volatile("s_waitcnt lgkmcnt(0)" ::: "memory");  // this wave's reads retired
    __builtin_amdgcn_s_barrier();                       // all waves done with buf[cur]
    cur ^= 1;
  }

  if constexpr (EPI == EPI_ROPE || EPI == EPI_QKV) {
    const int row0 = bm + wave * 16 + quad * 4;
    if (EPI == EPI_ROPE || bn < 1024) {
      // Q (or plain ROPE): -> C, ldc
#pragma unroll
      for (int r = 0; r < 4; ++r) {
        int row = row0 + r;
        int s = row & (S_ - 1);
#pragma unroll
        for (int ni = 0; ni < 2; ++ni) {
          int d = ni * 16 + l15;
          float c = cosT[s * 32 + d], sn = sinT[s * 32 + d];
          float x1 = acc[ni][r], x2 = acc[ni + 2][r];
          size_t base = (size_t)row * ldc + bn + ni * 16 + l15;
          ((uint16_t*)C)[base] = f2b(x1 * c - x2 * sn);
          ((uint16_t*)C)[base + 32] = f2b(x1 * sn + x2 * c);
        }
      }
    } else if (bn < 1280) {
      // K + RoPE -> C2 (kbuf), ldc 256
      uint16_t* kb = (uint16_t*)C2;
#pragma unroll
      for (int r = 0; r < 4; ++r) {
        int row = row0 + r;
        int s = row & (S_ - 1);
#pragma unroll
        for (int ni = 0; ni < 2; ++ni) {
          int d = ni * 16 + l15;
          float c = cosT[s * 32 + d], sn = sinT[s * 32 + d];
          float x1 = acc[ni][r], x2 = acc[ni + 2][r];
          size_t base = (size_t)row * 256 + (bn - 1024) + ni * 16 + l15;
          kb[base] = f2b(x1 * c - x2 * sn);
          kb[base + 32] = f2b(x1 * sn + x2 * c);
        }
      }
    } else {
      // V -> C3 (vtb), transposed [(b,kvh,d)][s]
      uint16_t* vb = (uint16_t*)C3;
#pragma unroll
      for (int ni = 0; ni < 4; ++ni)
#pragma unroll
        for (int r = 0; r < 4; ++r) {
          int row = row0 + r;
          int col3 = (bn - 1280) + ni * 16 + l15;
          int b = row >> 11, s = row & (S_ - 1);
          int kvh = col3 >> 6, d = col3 & 63;
          vb[(size_t)((b * HKV_ + kvh) * HD_ + d) * S_ + s] = f2b(acc[ni][r]);
        }
    }
  } else if constexpr (EPI == EPI_TRANSV) {
    const int row0 = bm + wave * 16 + quad * 4;
#pragma unroll
    for (int ni = 0; ni < 4; ++ni)
#pragma unroll
      for (int r = 0; r < 4; ++r) {
        int row = row0 + r;
        int col = bn + ni * 16 + l15;
        int b = row >> 11, s = row & (S_ - 1);
        int kvh = col >> 6, d = col & 63;
        ((uint16_t*)C)[(size_t)((b * HKV_ + kvh) * HD_ + d) * S_ + s] = f2b(acc[ni][r]);
      }
  } else {
    // 2x2 wave layout: wave covers rows wm*32..+31, cols wn*32..+31
    const int row0 = bm + wm * 32 + quad * 4;
#pragma unroll
    for (int mi = 0; mi < 2; ++mi)
#pragma unroll
      for (int ni = 0; ni < 2; ++ni) {
        int col = bn + wn * 32 + ni * 16 + l15;
#pragma unroll
        for (int r = 0; r < 4; ++r) {
          int row = row0 + mi * 16 + r;
          float v = acc[mi * 2 + ni][r];
          if constexpr (EPI == EPI_GELU) {
            v += ldr(bias, bias_off + col, f32);
            float z = 0.7978845608028654f * (v + 0.044715f * v * v * v);
            z = fminf(fmaxf(z, -15.f), 15.f);
            float e = __expf(-2.f * z);
            v = 0.5f * v * (1.f + (1.f - e) / (1.f + e));   // tanh gelu (jax default)
            ((uint16_t*)C)[(size_t)row * ldc + col] = f2b(v);
          } else if constexpr (EPI == EPI_RES) {
            v += ldr(res, (size_t)row * ldc + col, f32);
            str_(C, (size_t)row * ldc + col, v, f32);
          } else if constexpr (EPI == EPI_ACC) {
            if (bias) v += ldr(bias, bias_off + col, f32);
            v += ldr(C, (size_t)row * ldc + col, f32);   // accumulate (residual lives here)
            str_(C, (size_t)row * ldc + col, v, f32);
          }
        }
      }
  }
}

// ---------------- Flash attention ----------------
// v6 + T5 (R15): proven v6 structure (63.5us, 4x replicated) + s_setprio(1) around
// the MFMA clusters. m190: setprio null for barrier-synced waves WITHIN a block;
// here the mechanism is ACROSS the 2 independent blocks/CU at different phases —
// the MFMA-phase block preempts the staging-phase block (m191: +4-7% attn).
__global__ __launch_bounds__(256, 4) void attn_kernel(const uint16_t* __restrict__ q,
                                                      const uint16_t* __restrict__ k,
                                                      const uint16_t* __restrict__ vt,
                                                      uint16_t* __restrict__ o) {
  __shared__ __align__(16) uint16_t Ks[2][64 * 64];   // [key][dim] swizzled, 16 KB
  __shared__ __align__(16) uint16_t Vs[2][64 * 64];   // [d][key] swizzled, 16 KB
  __shared__ __align__(16) uint16_t Plds[4][16 * 64]; // per-wave P, 8 KB
  const int tid = threadIdx.x;
  const int wave = tid >> 6, lane = tid & 63;
  const int quad = lane >> 4, l15 = lane & 15;
  const int bid = blockIdx.x;                 // 0..511
  const int m = bid & 63;
  const int g = (bid >> 6) & 3;
  const int b = bid >> 8;
  const int h = g + 4 * wave;                 // this wave's q head (shares kv head g)

  const uint16_t* kbase = k + (size_t)(b * S_) * (HKV_ * HD_) + g * HD_;
  const uint16_t* vbase = vt + (size_t)((b * HKV_ + g) * HD_) * S_;
  f32x4 zero = {0.f, 0.f, 0.f, 0.f};

  const int arow = tid >> 3;                  // 0..31
  const int gcol = (tid & 7) ^ (arow & 7);
  const int woff = wave * 512;                // dest: wave*1024B + lane*16B (linear)
  uint16_t* pw = Plds[wave];

  auto stage = [&](int buf, int t) {
    const int kt = t << 6;
    gl16(kbase + (size_t)(kt + arow) * (HKV_ * HD_) + gcol * 8,      &Ks[buf][woff]);
    gl16(kbase + (size_t)(kt + 32 + arow) * (HKV_ * HD_) + gcol * 8, &Ks[buf][2048 + woff]);
    gl16(vbase + (size_t)arow * S_ + kt + gcol * 8,                  &Vs[buf][woff]);
    gl16(vbase + (size_t)(arow + 32) * S_ + kt + gcol * 8,           &Vs[buf][2048 + woff]);
  };

  int cur = 0;
  for (int seg = 0; seg < 2; ++seg) {
    const int qt = seg ? (127 - m) : m;       // nt(m)+nt(127-m) == 33, every block
    const int q0 = qt * 16;

    const uint16_t* qbase = q + (size_t)(b * S_ + q0 + l15) * D_ + h * HD_ + quad * 8;
    frag8 qa0 = *(const frag8*)qbase;         // Q[m=l15][d=quad*8..+7]
    frag8 qa1 = *(const frag8*)(qbase + 32);  // d+32

    f32x4 oacc[4];
#pragma unroll
    for (int i = 0; i < 4; i++) oacc[i] = zero;
    float m_i[4] = {-1e30f, -1e30f, -1e30f, -1e30f};
    float l_i[4] = {0.f, 0.f, 0.f, 0.f};

    const int nt = (q0 + 16 + 63) >> 6;       // same for all 4 waves of the block
    stage(cur, 0);
    __syncthreads();                          // vmcnt(0) at barrier: tile 0 staged
    for (int t = 0; t < nt; ++t) {
      const int kt = t << 6;
      if (t + 1 < nt) stage(cur ^ 1, t + 1);  // in flight under compute below

      // QK^T from LDS (swizzled read: slot c16 = logical ^ (row&7), row&7 == l15&7)
      f32x4 sc[4];
      __builtin_amdgcn_s_setprio(1);
#pragma unroll
      for (int f = 0; f < 4; ++f) {
        const int row = 16 * f + l15;
        frag8 kb0 = *(const frag8*)&Ks[cur][row * 64 + ((quad ^ (l15 & 7)) * 8)];
        frag8 kb1 = *(const frag8*)&Ks[cur][row * 64 + (((quad + 4) ^ (l15 & 7)) * 8)];
        f32x4 c = zero;
        c = __builtin_amdgcn_mfma_f32_16x16x32_bf16(qa0, kb0, c, 0, 0, 0);
        c = __builtin_amdgcn_mfma_f32_16x16x32_bf16(qa1, kb1, c, 0, 0, 0);
        sc[f] = c;
      }
      __builtin_amdgcn_s_setprio(0);
      const bool needmask = (kt + 63 > q0);
      float p[4][4];   // [fragment f][row r]; score row = q0+quad*4+r, key = kt+16f+l15
#pragma unroll
      for (int f = 0; f < 4; ++f)
#pragma unroll
        for (int r = 0; r < 4; ++r) p[f][r] = sc[f][r] * 0.125f;
      if (needmask) {
#pragma unroll
        for (int r = 0; r < 4; ++r) {
          int qq = q0 + quad * 4 + r;
#pragma unroll
          for (int f = 0; f < 4; ++f)
            if (kt + 16 * f + l15 > qq) p[f][r] = -1e30f;
        }
      }
      float alpha[4];
#pragma unroll
      for (int r = 0; r < 4; ++r) {
        float rm = fmaxf(fmaxf(p[0][r], p[1][r]), fmaxf(p[2][r], p[3][r]));
        rm = row16_max(rm);                        // DPP, VALU-speed
        float mn = fmaxf(m_i[r], rm);
        alpha[r] = __expf(m_i[r] - mn);
        m_i[r] = mn;
        float rs = 0.f;
#pragma unroll
        for (int f = 0; f < 4; ++f) { p[f][r] = __expf(p[f][r] - mn); rs += p[f][r]; }
        rs = row16_sum(rs);                        // DPP
        l_i[r] = l_i[r] * alpha[r] + rs;
      }
      // C-layout P -> A-layout via per-wave swizzled LDS round trip (row=q, col=key)
#pragma unroll
      for (int r = 0; r < 4; ++r) {
        int row = quad * 4 + r;
#pragma unroll
        for (int f = 0; f < 4; ++f)
          *(uint16_t*)((char*)pw + psw(row, f * 16 + l15)) = f2b(p[f][r]);
      }
      asm volatile("s_waitcnt lgkmcnt(0)" ::: "memory");
      frag8 pa0 = *(const frag8*)((const char*)pw + psw(l15, quad * 8));        // keys kt..+31
      frag8 pa1 = *(const frag8*)((const char*)pw + psw(l15, 32 + quad * 8));   // keys kt+32..+63
      __builtin_amdgcn_s_setprio(1);
#pragma unroll
      for (int d4 = 0; d4 < 4; ++d4) {
        const int row = d4 * 16 + l15;
        frag8 vb0 = *(const frag8*)&Vs[cur][row * 64 + ((quad ^ (l15 & 7)) * 8)];
        frag8 vb1 = *(const frag8*)&Vs[cur][row * 64 + (((quad + 4) ^ (l15 & 7)) * 8)];
        f32x4 t4 = oacc[d4];
#pragma unroll
        for (int r = 0; r < 4; ++r) t4[r] *= alpha[r];
        t4 = __builtin_amdgcn_mfma_f32_16x16x32_bf16(pa0, vb0, t4, 0, 0, 0);
        t4 = __builtin_amdgcn_mfma_f32_16x16x32_bf16(pa1, vb1, t4, 0, 0, 0);
        oacc[d4] = t4;
      }
      __builtin_amdgcn_s_setprio(0);
      __syncthreads();   // all waves done reading Ks/Vs[cur]; stage(t+1) drained (vmcnt0)
      cur ^= 1;
    }

#pragma unroll
    for (int d4 = 0; d4 < 4; ++d4)
#pragma unroll
      for (int r = 0; r < 4; ++r) {
        int row = b * S_ + q0 + quad * 4 + r;
        int col = h * HD_ + d4 * 16 + l15;
        o[(size_t)row * D_ + col] = f2b(oacc[d4][r] / l_i[r]);
      }
  }
}

// ---------------- launcher ----------------
extern "C" void kernel_launch(void* const* d_in, const int* in_sizes, int n_in,
                              void* d_out, int out_size, void* d_ws, size_t ws_size,
                              hipStream_t stream) {
  const void* x    = d_in[0];
  const void* wq   = d_in[2];
  const void* wk   = d_in[3];
  const void* wv   = d_in[4];
  const void* wo   = d_in[5];
  const void* ln1g = d_in[6];
  const void* ln1b = d_in[7];
  const void* ln2g = d_in[8];
  const void* ln2b = d_in[9];
  const void* w1   = d_in[10];
  const void* b1   = d_in[11];
  const void* w2   = d_in[12];
  const void* b2   = d_in[13];

  char* w = (char*)d_ws;
  // layout (bytes), total ~37.5 MB. wqT/wkT/wvT are deliberately CONTIGUOUS:
  // together they form Bt[1536][1024] for the merged QKV GEMM.
  int*      flag = (int*)w;                            // 4 B (padded to 4 KB)
  float*    cosT = (float*)(w + 4096);                 // 256 KB
  float*    sinT = (float*)(w + 266240);               // 256 KB
  uint16_t* wqT  = (uint16_t*)(w + 528384);            // 2 MB
  uint16_t* wkT  = (uint16_t*)(w + 2625536);           // 512 KB (= wqT + 2MB)
  uint16_t* wvT  = (uint16_t*)(w + 3149824);           // 512 KB (= wkT + 512KB)
  uint16_t* woT  = (uint16_t*)(w + 3674112);           // 2 MB
  uint16_t* hbuf = (uint16_t*)(w + 5771264);           // 8 MB
  uint16_t* qbuf = (uint16_t*)(w + 14159872);          // 8 MB   } w1T after attn
  uint16_t* kbuf = (uint16_t*)(w + 22548480);          // 2 MB   } w2T after RES gemm
  uint16_t* vtb  = (uint16_t*)(w + 24645632);          // 2 MB   }
  uint16_t* obuf = (uint16_t*)(w + 26742784);          // 8 MB   }
  uint16_t* w1T  = (uint16_t*)(w + 14159872);          // 8 MB (over dead qbuf)
  uint16_t* w2T  = (uint16_t*)(w + 22548480);          // 8 MB, ends at 30937088
  uint16_t* hidq = (uint16_t*)(w + 30937088);          // 8 MB, AFTER w2T

  detect_kernel<<<dim3(1), dim3(64), 0, stream>>>((const uint16_t*)x, flag);
  rope_table_kernel<<<dim3(256), dim3(256), 0, stream>>>(cosT, sinT);

  transpose_k<<<dim3(32, 32), dim3(256), 0, stream>>>(wq, wqT, 1024, 1024, flag);
  transpose_k<<<dim3(8, 32), dim3(256), 0, stream>>>(wk, wkT, 1024, 256, flag);
  transpose_k<<<dim3(8, 32), dim3(256), 0, stream>>>(wv, wvT, 1024, 256, flag);
  transpose_k<<<dim3(32, 32), dim3(256), 0, stream>>>(wo, woT, 1024, 1024, flag);

  ln_kernel<<<dim3(4096), dim3(256), 0, stream>>>(x, ln1g, ln1b, hbuf, flag);

  // merged QKV: N=1536 over contiguous wqT|wkT|wvT; epilogue branches on bn
  gemm_bt<EPI_QKV><<<dim3(64, 24), dim3(256), 0, stream>>>(hbuf, 1024, wqT, 1024, qbuf, 1024,
      4096, 1536, 1024, cosT, sinT, nullptr, 0, nullptr, nullptr, kbuf, vtb);

  attn_kernel<<<dim3(512), dim3(256), 0, stream>>>(qbuf, kbuf, vtb, obuf);

  transpose_k<<<dim3(128, 32), dim3(256), 0, stream>>>(w1, w1T, 1024, 4096, flag);

  gemm_bt<EPI_RES><<<dim3(64, 16), dim3(256), 0, stream>>>(obuf, 1024, woT, 1024, d_out, 1024,
      4096, 1024, 1024, nullptr, nullptr, nullptr, 0, x, flag, nullptr, nullptr);

  transpose_k<<<dim3(32, 128), dim3(256), 0, stream>>>(w2, w2T, 4096, 1024, flag);

  ln_kernel<<<dim3(4096), dim3(256), 0, stream>>>(d_out, ln2g, ln2b, hbuf, flag);

  // MLP in 4 P-chunks: hidq = gelu(hbuf @ w1T_chunk + b1_chunk); d_out += hidq @ w2T_chunk
  for (int j = 0; j < 4; ++j) {
    const uint16_t* w1c = w1T + (size_t)j * 1024 * 1024;
    const uint16_t* w2c = w2T + (size_t)j * 1024;
    const void* bb = (j == 0) ? b2 : nullptr;
    gemm_bt<EPI_GELU><<<dim3(64, 16), dim3(256), 0, stream>>>(hbuf, 1024, w1c, 1024, hidq, 1024,
        4096, 1024, 1024, nullptr, nullptr, b1, j * 1024, nullptr, flag, nullptr, nullptr);
    gemm_bt<EPI_ACC><<<dim3(64, 16), dim3(256), 0, stream>>>(hidq, 1024, w2c, 4096, d_out, 1024,
        4096, 1024, 1024, nullptr, nullptr, bb, 0, nullptr, flag, nullptr, nullptr);
  }
}